// Round 12
// baseline (1476.804 us; speedup 1.0000x reference)
//
#include <hip/hip_runtime.h>
#include <hip/hip_fp16.h>
#include <stdint.h>

typedef _Float16 f16x8 __attribute__((ext_vector_type(8)));
typedef float f32x4 __attribute__((ext_vector_type(4)));

constexpr int NN  = 50000;   // nodes
constexpr int NE  = 800000;  // edges
constexpr int NG  = 64;      // graphs
constexpr int H   = 300;     // hidden
constexpr int H2  = 600;     // 2*hidden
constexpr int IND = 20;      // 2*PERIOD
constexpr int NL  = 5;

constexpr int MP  = 50048;   // rows padded to multiple of 128
constexpr int KP1 = 320;     // padded K stride for agg/u buffers (mult of 32)
constexpr int KP2 = 608;     // padded K stride for t buffers (mult of 32)
constexpr int NP1 = 640;     // padded N for gemm1 (5 x 128)
constexpr int NP2 = 384;     // padded N for gemm2 (3 x 128)
constexpr int HCS = 320;     // hc (fp16 h copy) row stride

constexpr int SCAN_B = (NN + 1023) / 1024;  // 49 scan blocks

// ---------------- fp16 helpers ----------------
static __device__ __forceinline__ ushort f2h(float f) {
  return __half_as_ushort(__float2half(f));
}
static __device__ __forceinline__ float h2f_lo(uint32_t u) {
  return __half2float(__ushort_as_half((ushort)(u & 0xFFFFu)));
}
static __device__ __forceinline__ float h2f_hi(uint32_t u) {
  return __half2float(__ushort_as_half((ushort)(u >> 16)));
}
static __device__ __forceinline__ uint32_t packh(float a, float b) {
  return (uint32_t)f2h(a) | ((uint32_t)f2h(b) << 16);
}

// ---------------- edge sort (counting sort by dst) ----------------

__global__ void hist_kernel(const int* __restrict__ dst, int* __restrict__ hist) {
  int i = blockIdx.x * blockDim.x + threadIdx.x;
  if (i < NE) atomicAdd(&hist[dst[i]], 1);
}

// multi-block scan (round-9 lesson: single-block scan = 92 us at 0.17% occupancy)
__global__ __launch_bounds__(1024) void scan1_kernel(const int* __restrict__ hist,
                                                     int* __restrict__ offs,
                                                     int* __restrict__ bsum) {
  __shared__ int sdata[1024];
  int b = blockIdx.x, tid = threadIdx.x;
  int i = b * 1024 + tid;
  int v = (i < NN) ? hist[i] : 0;
  sdata[tid] = v;
  __syncthreads();
  for (int ofs = 1; ofs < 1024; ofs <<= 1) {
    int t = (tid >= ofs) ? sdata[tid - ofs] : 0;
    __syncthreads();
    sdata[tid] += t;
    __syncthreads();
  }
  if (i < NN) offs[i] = sdata[tid] - v;  // exclusive within block
  if (tid == 1023) bsum[b] = sdata[1023];
}

__global__ void scan2_kernel(const int* __restrict__ bsum, int* __restrict__ bpre) {
  if (threadIdx.x == 0) {
    int run = 0;
    for (int b = 0; b < SCAN_B; ++b) {
      bpre[b] = run;
      run += bsum[b];
    }
    bpre[SCAN_B] = run;  // = NE
  }
}

__global__ __launch_bounds__(1024) void scan3_kernel(const int* __restrict__ bpre,
                                                     int* __restrict__ offs,
                                                     int* __restrict__ cursor) {
  int b = blockIdx.x, tid = threadIdx.x;
  int i = b * 1024 + tid;
  if (i < NN) {
    int o = offs[i] + bpre[b];
    offs[i] = o;
    cursor[i] = o;
  }
  if (i == 0) offs[NN] = bpre[SCAN_B];
}

__global__ void scatter_kernel(const int* __restrict__ src, const int* __restrict__ dst,
                               const float* __restrict__ w, int* __restrict__ cursor,
                               int* __restrict__ ssrc, float* __restrict__ sw) {
  int i = blockIdx.x * blockDim.x + threadIdx.x;
  if (i < NE) {
    int d = dst[i];
    int p = atomicAdd(&cursor[d], 1);
    ssrc[p] = src[i];
    sw[p]   = w[i];
  }
}

// ---------------- pad zeroing (single fp16 buffer) ----------------

__global__ void padzero_kernel(ushort* __restrict__ b, int KPAD, int Ntrue) {
  long long nA = (long long)(MP - NN) * KPAD;
  int padc = KPAD - Ntrue;
  long long nB = (long long)NN * padc;
  long long total = nA + nB;
  long long stride = (long long)gridDim.x * blockDim.x;
  for (long long i = blockIdx.x * (long long)blockDim.x + threadIdx.x; i < total; i += stride) {
    long long off;
    if (i < nA) {
      off = (long long)NN * KPAD + i;
    } else {
      long long j = i - nA;
      long long r = j / padc;
      long long c = Ntrue + (j - r * padc);
      off = r * KPAD + c;
    }
    b[off] = 0;
  }
}

// ---------------- weight pre-pack (fp16): Bp[n][k] = fp16(W[k][n]) ----------------

__global__ void packW1_kernel(const float* __restrict__ W1s, ushort* __restrict__ Wp) {
  int idx = blockIdx.x * blockDim.x + threadIdx.x;
  if (idx >= NL * NP1 * KP1) return;
  int i = idx / (NP1 * KP1);
  int rem = idx - i * (NP1 * KP1);
  int n = rem / KP1;
  int k = rem - n * KP1;
  float v = (n < H2 && k < H) ? W1s[((long long)i * H + k) * H2 + n] : 0.f;
  Wp[idx] = f2h(v);
}

__global__ void packW2_kernel(const float* __restrict__ W2s, ushort* __restrict__ Wp) {
  int idx = blockIdx.x * blockDim.x + threadIdx.x;
  if (idx >= NL * NP2 * KP2) return;
  int i = idx / (NP2 * KP2);
  int rem = idx - i * (NP2 * KP2);
  int n = rem / KP2;
  int k = rem - n * KP2;
  float v = (n < H && k < H2) ? W2s[((long long)i * H2 + k) * H + n] : 0.f;
  Wp[idx] = f2h(v);
}

// ---------------- input linear: hc = fp16(x @ linW + linb), LDS-staged W ----------------

__global__ __launch_bounds__(256) void lin_kernel(const float* __restrict__ x,
                                                  const float* __restrict__ W,
                                                  const float* __restrict__ b,
                                                  ushort* __restrict__ hc) {
  __shared__ float Ws[IND * H];  // 24 KB
  __shared__ float bs[H];
  int tid = threadIdx.x;
  for (int i = tid; i < IND * H; i += 256) Ws[i] = W[i];
  for (int i = tid; i < H; i += 256) bs[i] = b[i];
  __syncthreads();
  const int QPR = H / 4;  // 75 quads per row
  int total = NN * QPR;
  for (int idx = blockIdx.x * 256 + tid; idx < total; idx += gridDim.x * 256) {
    int n = idx / QPR;
    int f = (idx - n * QPR) * 4;
    float a0 = bs[f], a1 = bs[f + 1], a2 = bs[f + 2], a3 = bs[f + 3];
    const float* xr = x + n * IND;
#pragma unroll
    for (int k = 0; k < IND; ++k) {
      float xv = xr[k];
      const float* wk = &Ws[k * H + f];
      a0 = fmaf(xv, wk[0], a0);
      a1 = fmaf(xv, wk[1], a1);
      a2 = fmaf(xv, wk[2], a2);
      a3 = fmaf(xv, wk[3], a3);
    }
    uint2 o = make_uint2(packh(a0, a1), packh(a2, a3));
    *reinterpret_cast<uint2*>(hc + (long long)n * HCS + f) = o;
  }
}

// ---------------- aggregation: fp16 hc gather (8-deep), fp16 agg out ----------------

__global__ __launch_bounds__(192) void agg_kernel(const ushort* __restrict__ hc,
                                                  const int* __restrict__ offs,
                                                  const int* __restrict__ ssrc,
                                                  const float* __restrict__ sw,
                                                  ushort* __restrict__ agg) {
  int n = blockIdx.x;
  int t = threadIdx.x;
  if (t >= H / 2) return;
  int s = offs[n], e = offs[n + 1];
  float a0 = 0.f, a1 = 0.f;
  int i = s;
  for (; i + 7 < e; i += 8) {
    uint32_t u[8];
    float w[8];
#pragma unroll
    for (int j = 0; j < 8; ++j) {
      int sn = ssrc[i + j];
      w[j] = sw[i + j];
      u[j] = *reinterpret_cast<const uint32_t*>(hc + (long long)sn * HCS + 2 * t);
    }
#pragma unroll
    for (int j = 0; j < 8; ++j) {
      a0 = fmaf(w[j], h2f_lo(u[j]), a0);
      a1 = fmaf(w[j], h2f_hi(u[j]), a1);
    }
  }
  for (; i < e; ++i) {
    int sn = ssrc[i];
    float w = sw[i];
    uint32_t u = *reinterpret_cast<const uint32_t*>(hc + (long long)sn * HCS + 2 * t);
    a0 = fmaf(w, h2f_lo(u), a0);
    a1 = fmaf(w, h2f_hi(u), a1);
  }
  *reinterpret_cast<uint32_t*>(agg + (long long)n * KP1 + 2 * t) = packh(a0, a1);
}

// ---------------- fp16 MFMA GEMM, LDS-staged A, fused stats, XCD swizzle ----------------
// FUSE_BN: apply per-k relu(bns[k]*a + bnh[k]) to A fragments in-register, using native
// _Float16 ext-vector arithmetic (round-11 lesson: ROCm __hmax2/__hfma2 overloads do not
// accept __half2 here). Both-sides swizzle => fragment a[i] holds k = kt*32 + lg*8 + j.
// launch_bounds (256,4): NO spills (round-8 lesson: (256,6) -> VGPR=40 full spill, 5x).

template <bool FUSE_BN>
__global__ __launch_bounds__(256, 4) void gemm_mfma(
    const ushort* __restrict__ A, const ushort* __restrict__ Bp,
    const float* __restrict__ bias, ushort* __restrict__ C,
    float* __restrict__ sum, float* __restrict__ sq,
    int M, int Ntrue, int Ktiles, int KPAD, int Cstride, int ntiles,
    const ushort* __restrict__ bns, const ushort* __restrict__ bnh) {
  __shared__ ushort AL[2][128 * 32];
  int nwg = gridDim.x;
  int hw = blockIdx.x;
  int xcd = hw & 7, slot = hw >> 3;
  int q = nwg >> 3, r = nwg & 7;
  int logical = (xcd < r ? xcd * (q + 1) : r * (q + 1) + (xcd - r) * q) + slot;
  int mt = logical / ntiles;
  int nt = logical - mt * ntiles;

  int tid = threadIdx.x;
  int lane = tid & 63, wid = tid >> 6;
  int wm = wid >> 1, wn = wid & 1;
  int lm = lane & 15, lg = lane >> 4;
  long long bm = (long long)mt * 128;
  long long bn = (long long)nt * 128;

  int srow = lane >> 2;   // 0..15: row within the wave's 16-row staging segment
  int slotc = lane & 3;   // 16-byte chunk slot

  const ushort* Bb = Bp + (bn + wn * 64 + lm) * KPAD + lg * 8;

  f32x4 acc[4][4] = {};

  auto stageA = [&](int buf, int kt) {
    int k0 = kt * 32;
#pragma unroll
    for (int j = 0; j < 2; ++j) {
      int row = j * 64 + wid * 16 + srow;
      int cg = slotc ^ ((row >> 1) & 3);   // swizzled source chunk
      long long go = (bm + row) * KPAD + k0 + cg * 8;
      ushort* l = &AL[buf][(j * 64 + wid * 16) * 32];  // wave-uniform base
      __builtin_amdgcn_global_load_lds(
          (const __attribute__((address_space(1))) void*)(A + go),
          (__attribute__((address_space(3))) void*)l, 16, 0, 0);
    }
  };

  f16x8 bcur[4], bnxt[4];
  stageA(0, 0);
#pragma unroll
  for (int i = 0; i < 4; ++i)
    bcur[i] = *reinterpret_cast<const f16x8*>(Bb + (long long)i * 16 * KPAD);
  __syncthreads();

  for (int kt = 0; kt < Ktiles; ++kt) {
    int cur = kt & 1;
    int nk = kt + 1;
    if (nk < Ktiles) {
      stageA(nk & 1, nk);
#pragma unroll
      for (int i = 0; i < 4; ++i)
        bnxt[i] = *reinterpret_cast<const f16x8*>(Bb + (long long)i * 16 * KPAD + nk * 32);
    }
    f16x8 a[4];
#pragma unroll
    for (int i = 0; i < 4; ++i) {
      int row = wm * 64 + i * 16 + lm;
      int c = lg ^ ((row >> 1) & 3);
      a[i] = *reinterpret_cast<const f16x8*>(&AL[cur][row * 32 + c * 8]);
    }
    if constexpr (FUSE_BN) {
      int kbase = kt * 32 + lg * 8;
      f16x8 sv = *reinterpret_cast<const f16x8*>(bns + kbase);
      f16x8 hv = *reinterpret_cast<const f16x8*>(bnh + kbase);
#pragma unroll
      for (int i = 0; i < 4; ++i) {
        f16x8 t = a[i] * sv + hv;
#pragma unroll
        for (int j = 0; j < 8; ++j) t[j] = t[j] > (_Float16)0 ? t[j] : (_Float16)0;
        a[i] = t;
      }
    }
#pragma unroll
    for (int mf = 0; mf < 4; ++mf)
#pragma unroll
      for (int nf = 0; nf < 4; ++nf)
        acc[mf][nf] = __builtin_amdgcn_mfma_f32_16x16x32_f16(a[mf], bcur[nf], acc[mf][nf], 0, 0, 0);
    __syncthreads();
#pragma unroll
    for (int i = 0; i < 4; ++i) bcur[i] = bnxt[i];
  }

  int colb = (int)bn + wn * 64 + lm;
#pragma unroll
  for (int nf = 0; nf < 4; ++nf) {
    int col = colb + nf * 16;
    bool cok = col < Ntrue;   // Ntrue even -> pair (col, col+1) valid together
    float bv = cok ? bias[col] : 0.f;
    float cs = 0.f, cq = 0.f;
#pragma unroll
    for (int mf = 0; mf < 4; ++mf) {
      int row0 = (int)bm + wm * 64 + mf * 16 + lg * 4;
      f32x4 v = acc[mf][nf];
#pragma unroll
      for (int e = 0; e < 4; ++e) {
        float w = v[e] + bv;
        bool ok = cok && (row0 + e < M);
        if (ok) {
          cs += w;
          cq = fmaf(w, w, cq);
        }
        float wp = __shfl_xor(w, 1);  // partner column's value, same row
        if (ok && ((lm & 1) == 0)) {
          *reinterpret_cast<uint32_t*>(&C[(long long)(row0 + e) * Cstride + col]) = packh(w, wp);
        }
      }
    }
    cs += __shfl_xor(cs, 16);
    cq += __shfl_xor(cq, 16);
    cs += __shfl_xor(cs, 32);
    cq += __shfl_xor(cq, 32);
    if (lg == 0 && cok) {
      atomicAdd(&sum[col], cs);
      atomicAdd(&sq[col], cq);
    }
  }
}

// ---------------- BN finalize ----------------
// Writes f32 scale/shift (and optionally packed fp16 copies for the fused gemm2 path).
// Zero-fills [C, Calloc) so padded-K fragments come out exactly 0 after fused BN.

__global__ void finalize_kernel(const float* __restrict__ sum, const float* __restrict__ sq,
                                const float* __restrict__ g, const float* __restrict__ be,
                                int C, int Calloc, float invM, float* __restrict__ scale,
                                float* __restrict__ shift, ushort* __restrict__ scaleh,
                                ushort* __restrict__ shifth) {
  int c = blockIdx.x * blockDim.x + threadIdx.x;
  if (c >= Calloc) return;
  float sc = 0.f, sh = 0.f;
  if (c < C) {
    float m = sum[c] * invM;
    float v = sq[c] * invM - m * m;
    sc = g[c] * rsqrtf(v + 1e-5f);
    sh = be[c] - m * sc;
  }
  scale[c] = sc;
  shift[c] = sh;
  if (scaleh) {
    scaleh[c] = f2h(sc);
    shifth[c] = f2h(sh);
  }
}

// bn2: fp16 u (stride KP1) -> fp16 hc (intermediate) or f32 hout (last)
template <bool LAST>
__global__ void bn2_kernel(const ushort* __restrict__ u_, const float* __restrict__ scale,
                           const float* __restrict__ shift, ushort* __restrict__ hc,
                           float* __restrict__ out) {
  const int QPR = H / 4;  // 75
  int total = NN * QPR;
  for (int idx = blockIdx.x * blockDim.x + threadIdx.x; idx < total;
       idx += gridDim.x * blockDim.x) {
    int r = idx / QPR;
    int c = (idx - r * QPR) * 4;
    uint2 u = *reinterpret_cast<const uint2*>(u_ + (long long)r * KP1 + c);
    float4 sc = *reinterpret_cast<const float4*>(scale + c);
    float4 sh = *reinterpret_cast<const float4*>(shift + c);
    float w0 = fmaf(h2f_lo(u.x), sc.x, sh.x);
    float w1 = fmaf(h2f_hi(u.x), sc.y, sh.y);
    float w2 = fmaf(h2f_lo(u.y), sc.z, sh.z);
    float w3 = fmaf(h2f_hi(u.y), sc.w, sh.w);
    if (LAST) {
      *reinterpret_cast<float4*>(out + (long long)r * H + c) = make_float4(w0, w1, w2, w3);
    } else {
      w0 = fmaxf(w0, 0.f);
      w1 = fmaxf(w1, 0.f);
      w2 = fmaxf(w2, 0.f);
      w3 = fmaxf(w3, 0.f);
      *reinterpret_cast<uint2*>(hc + (long long)r * HCS + c) =
          make_uint2(packh(w0, w1), packh(w2, w3));
    }
  }
}

// ---------------- graph pooling ----------------

__global__ void bounds_kernel(const int* __restrict__ batch, int* __restrict__ gstart) {
  int g = threadIdx.x;
  if (g > NG) return;
  if (g == NG) { gstart[NG] = NN; return; }
  int lo = 0, hi = NN;
  while (lo < hi) {
    int mid = (lo + hi) >> 1;
    if (batch[mid] < g) lo = mid + 1; else hi = mid;
  }
  gstart[g] = lo;
}

__global__ __launch_bounds__(320) void pool_kernel(const float* __restrict__ h,
                                                   const int* __restrict__ gstart,
                                                   float* __restrict__ xpool) {
  int g = blockIdx.x;
  int f = threadIdx.x;
  if (f >= H) return;
  int s = gstart[g], e = gstart[g + 1];
  float acc = 0.f;
  for (int r = s + blockIdx.y; r < e; r += gridDim.y) acc += h[(long long)r * H + f];
  atomicAdd(&xpool[g * H + f], acc);
}

// ---------------- driver ----------------

extern "C" void kernel_launch(void* const* d_in, const int* in_sizes, int n_in,
                              void* d_out, int out_size, void* d_ws, size_t ws_size,
                              hipStream_t stream) {
  const int*   batch = (const int*)d_in[0];
  const float* x     = (const float*)d_in[1];
  const int*   eidx  = (const int*)d_in[2];
  const float* eattr = (const float*)d_in[3];
  const float* linW  = (const float*)d_in[4];
  const float* linb  = (const float*)d_in[5];
  const float* W1s   = (const float*)d_in[6];
  const float* b1s   = (const float*)d_in[7];
  const float* g1s   = (const float*)d_in[8];
  const float* be1s  = (const float*)d_in[9];
  const float* W2s   = (const float*)d_in[10];
  const float* b2s   = (const float*)d_in[11];
  const float* gos   = (const float*)d_in[12];
  const float* bos   = (const float*)d_in[13];

  const int* esrc = eidx;
  const int* edst = eidx + NE;

  char* p = (char*)d_ws;
  auto alloc = [&](size_t bytes) {
    char* r = p;
    p += (bytes + 255) & ~(size_t)255;
    return r;
  };
  ushort* tb   = (ushort*)alloc((size_t)MP * KP2 * 2);   // t (fp16)
  ushort* ub   = (ushort*)alloc((size_t)MP * KP1 * 2);   // agg, reused as u (fp16)
  ushort* hc   = (ushort*)alloc((size_t)NN * HCS * 2);   // fp16 h copy
  ushort* W1p  = (ushort*)alloc((size_t)NL * NP1 * KP1 * 2);
  ushort* W2p  = (ushort*)alloc((size_t)NL * NP2 * KP2 * 2);
  int*    hist   = (int*)alloc((size_t)NN * 4);
  int*    offs   = (int*)alloc((size_t)(NN + 64) * 4);
  int*    cursor = (int*)alloc((size_t)NN * 4);
  int*    ssrc   = (int*)alloc((size_t)NE * 4);
  float*  sw     = (float*)alloc((size_t)NE * 4);
  int*    bsum   = (int*)alloc((size_t)(SCAN_B + 1) * 4);
  int*    bpre   = (int*)alloc((size_t)(SCAN_B + 1) * 4);
  float*  sum1   = (float*)alloc((size_t)(H2 * 2 + H * 2) * 4);
  float*  sq1    = sum1 + H2;
  float*  sum2   = sq1 + H2;
  float*  sq2    = sum2 + H;
  float*  scale1 = (float*)alloc((size_t)(KP2 * 2 + H * 2) * 4);
  float*  shift1 = scale1 + KP2;
  float*  scale2 = shift1 + KP2;
  float*  shift2 = scale2 + H;
  ushort* scaleh = (ushort*)alloc((size_t)KP2 * 2 * 2);  // packed fp16 scale/shift
  ushort* shifth = scaleh + KP2;
  int*    gstart = (int*)alloc((size_t)(NG + 1) * 4);
  size_t needed = (size_t)(p - (char*)d_ws);
  if (ws_size < needed) return;

  float* hout  = (float*)d_out;
  float* xpool = hout + (long long)NN * H;

  padzero_kernel<<<1024, 256, 0, stream>>>(tb, KP2, H2);
  padzero_kernel<<<1024, 256, 0, stream>>>(ub, KP1, H);

  packW1_kernel<<<(NL * NP1 * KP1 + 255) / 256, 256, 0, stream>>>(W1s, W1p);
  packW2_kernel<<<(NL * NP2 * KP2 + 255) / 256, 256, 0, stream>>>(W2s, W2p);

  hipMemsetAsync(hist, 0, (size_t)NN * 4, stream);
  hist_kernel<<<(NE + 255) / 256, 256, 0, stream>>>(edst, hist);
  scan1_kernel<<<SCAN_B, 1024, 0, stream>>>(hist, offs, bsum);
  scan2_kernel<<<1, 64, 0, stream>>>(bsum, bpre);
  scan3_kernel<<<SCAN_B, 1024, 0, stream>>>(bpre, offs, cursor);
  scatter_kernel<<<(NE + 255) / 256, 256, 0, stream>>>(esrc, edst, eattr, cursor, ssrc, sw);

  lin_kernel<<<4096, 256, 0, stream>>>(x, linW, linb, hc);

  const int MT = MP / 128;  // 391
  for (int i = 0; i < NL; ++i) {
    agg_kernel<<<NN, 192, 0, stream>>>(hc, offs, ssrc, sw, ub);
    hipMemsetAsync(sum1, 0, (size_t)(H2 * 2 + H * 2) * 4, stream);

    // t = agg @ W1 + b1  (fp16 out, stats fused)
    gemm_mfma<false><<<MT * (NP1 / 128), 256, 0, stream>>>(
        ub, W1p + (size_t)i * NP1 * KP1, b1s + (size_t)i * H2, tb,
        sum1, sq1, NN, H2, KP1 / 32, KP1, KP2, NP1 / 128, nullptr, nullptr);
    // BN1 scale/shift, incl. packed fp16 + zeroed K-pad for the fused gemm2 path
    finalize_kernel<<<(KP2 + 255) / 256, 256, 0, stream>>>(
        sum1, sq1, g1s + (size_t)i * H2, be1s + (size_t)i * H2, H2, KP2, 1.f / NN,
        scale1, shift1, scaleh, shifth);

    // u = relu(bn1(t)) @ W2 + b2 — BN1 fused into A-fragment path (no bn1 pass)
    gemm_mfma<true><<<MT * (NP2 / 128), 256, 0, stream>>>(
        tb, W2p + (size_t)i * NP2 * KP2, b2s + (size_t)i * H, ub,
        sum2, sq2, NN, H, KP2 / 32, KP2, KP1, NP2 / 128, scaleh, shifth);
    finalize_kernel<<<(H + 255) / 256, 256, 0, stream>>>(
        sum2, sq2, gos + (size_t)i * H, bos + (size_t)i * H, H, H, 1.f / NN,
        scale2, shift2, nullptr, nullptr);
    if (i < NL - 1) {
      bn2_kernel<false><<<4096, 256, 0, stream>>>(ub, scale2, shift2, hc, hout);
    } else {
      bn2_kernel<true><<<4096, 256, 0, stream>>>(ub, scale2, shift2, hc, hout);
    }
  }

  hipMemsetAsync(xpool, 0, (size_t)NG * H * 4, stream);
  bounds_kernel<<<1, 128, 0, stream>>>(batch, gstart);
  pool_kernel<<<dim3(NG, 8), 320, 0, stream>>>(hout, gstart, xpool);
}

// Round 13
// 1351.078 us; speedup vs baseline: 1.0931x; 1.0931x over previous
//
#include <hip/hip_runtime.h>
#include <hip/hip_fp16.h>
#include <stdint.h>

typedef _Float16 f16x8 __attribute__((ext_vector_type(8)));
typedef unsigned short u16x8 __attribute__((ext_vector_type(8)));
typedef float f32x4 __attribute__((ext_vector_type(4)));

constexpr int NN  = 50000;   // nodes
constexpr int NE  = 800000;  // edges
constexpr int NG  = 64;      // graphs
constexpr int H   = 300;     // hidden
constexpr int H2  = 600;     // 2*hidden
constexpr int IND = 20;      // 2*PERIOD
constexpr int NL  = 5;

constexpr int MP  = 50048;   // rows padded to multiple of 128
constexpr int KP1 = 320;     // padded K stride for agg/u buffers (mult of 32)
constexpr int KP2 = 608;     // padded K stride for t buffers (mult of 32)
constexpr int NP1 = 640;     // padded N for gemm1 (5 x 128)
constexpr int NP2 = 384;     // padded N for gemm2 (3 x 128)
constexpr int HCS = 320;     // hc (fp16 h copy) row stride

constexpr int SCAN_B = (NN + 1023) / 1024;  // 49 scan blocks

// ---------------- fp16 helpers ----------------
static __device__ __forceinline__ ushort f2h(float f) {
  return __half_as_ushort(__float2half(f));
}
static __device__ __forceinline__ float h2f_lo(uint32_t u) {
  return __half2float(__ushort_as_half((ushort)(u & 0xFFFFu)));
}
static __device__ __forceinline__ float h2f_hi(uint32_t u) {
  return __half2float(__ushort_as_half((ushort)(u >> 16)));
}
static __device__ __forceinline__ uint32_t packh(float a, float b) {
  return (uint32_t)f2h(a) | ((uint32_t)f2h(b) << 16);
}

// packed relu on f16x8 (round-12 lesson: scalar lane ops on ext_vector
// lower to serial extract/insert chains; use elementwise builtin -> v_pk_max_f16)
static __device__ __forceinline__ f16x8 relu8(f16x8 t) {
#if __has_builtin(__builtin_elementwise_max)
  f16x8 z = 0;
  return __builtin_elementwise_max(t, z);
#else
  u16x8 u = *reinterpret_cast<u16x8*>(&t);
  u = u & (u16x8)((u >> 15) - (unsigned short)1);
  return *reinterpret_cast<f16x8*>(&u);
#endif
}

// ---------------- edge sort (counting sort by dst) ----------------

__global__ void hist_kernel(const int* __restrict__ dst, int* __restrict__ hist) {
  int i = blockIdx.x * blockDim.x + threadIdx.x;
  if (i < NE) atomicAdd(&hist[dst[i]], 1);
}

// multi-block scan (round-9 lesson: single-block scan = 92 us at 0.17% occupancy)
__global__ __launch_bounds__(1024) void scan1_kernel(const int* __restrict__ hist,
                                                     int* __restrict__ offs,
                                                     int* __restrict__ bsum) {
  __shared__ int sdata[1024];
  int b = blockIdx.x, tid = threadIdx.x;
  int i = b * 1024 + tid;
  int v = (i < NN) ? hist[i] : 0;
  sdata[tid] = v;
  __syncthreads();
  for (int ofs = 1; ofs < 1024; ofs <<= 1) {
    int t = (tid >= ofs) ? sdata[tid - ofs] : 0;
    __syncthreads();
    sdata[tid] += t;
    __syncthreads();
  }
  if (i < NN) offs[i] = sdata[tid] - v;  // exclusive within block
  if (tid == 1023) bsum[b] = sdata[1023];
}

__global__ void scan2_kernel(const int* __restrict__ bsum, int* __restrict__ bpre) {
  if (threadIdx.x == 0) {
    int run = 0;
    for (int b = 0; b < SCAN_B; ++b) {
      bpre[b] = run;
      run += bsum[b];
    }
    bpre[SCAN_B] = run;  // = NE
  }
}

__global__ __launch_bounds__(1024) void scan3_kernel(const int* __restrict__ bpre,
                                                     int* __restrict__ offs,
                                                     int* __restrict__ cursor) {
  int b = blockIdx.x, tid = threadIdx.x;
  int i = b * 1024 + tid;
  if (i < NN) {
    int o = offs[i] + bpre[b];
    offs[i] = o;
    cursor[i] = o;
  }
  if (i == 0) offs[NN] = bpre[SCAN_B];
}

__global__ void scatter_kernel(const int* __restrict__ src, const int* __restrict__ dst,
                               const float* __restrict__ w, int* __restrict__ cursor,
                               int* __restrict__ ssrc, float* __restrict__ sw) {
  int i = blockIdx.x * blockDim.x + threadIdx.x;
  if (i < NE) {
    int d = dst[i];
    int p = atomicAdd(&cursor[d], 1);
    ssrc[p] = src[i];
    sw[p]   = w[i];
  }
}

// ---------------- pad zeroing (single fp16 buffer) ----------------

__global__ void padzero_kernel(ushort* __restrict__ b, int KPAD, int Ntrue) {
  long long nA = (long long)(MP - NN) * KPAD;
  int padc = KPAD - Ntrue;
  long long nB = (long long)NN * padc;
  long long total = nA + nB;
  long long stride = (long long)gridDim.x * blockDim.x;
  for (long long i = blockIdx.x * (long long)blockDim.x + threadIdx.x; i < total; i += stride) {
    long long off;
    if (i < nA) {
      off = (long long)NN * KPAD + i;
    } else {
      long long j = i - nA;
      long long r = j / padc;
      long long c = Ntrue + (j - r * padc);
      off = r * KPAD + c;
    }
    b[off] = 0;
  }
}

// ---------------- weight pre-pack (fp16): Bp[n][k] = fp16(W[k][n]) ----------------

__global__ void packW1_kernel(const float* __restrict__ W1s, ushort* __restrict__ Wp) {
  int idx = blockIdx.x * blockDim.x + threadIdx.x;
  if (idx >= NL * NP1 * KP1) return;
  int i = idx / (NP1 * KP1);
  int rem = idx - i * (NP1 * KP1);
  int n = rem / KP1;
  int k = rem - n * KP1;
  float v = (n < H2 && k < H) ? W1s[((long long)i * H + k) * H2 + n] : 0.f;
  Wp[idx] = f2h(v);
}

__global__ void packW2_kernel(const float* __restrict__ W2s, ushort* __restrict__ Wp) {
  int idx = blockIdx.x * blockDim.x + threadIdx.x;
  if (idx >= NL * NP2 * KP2) return;
  int i = idx / (NP2 * KP2);
  int rem = idx - i * (NP2 * KP2);
  int n = rem / KP2;
  int k = rem - n * KP2;
  float v = (n < H && k < H2) ? W2s[((long long)i * H2 + k) * H + n] : 0.f;
  Wp[idx] = f2h(v);
}

// ---------------- input linear: hc = fp16(x @ linW + linb), LDS-staged W ----------------

__global__ __launch_bounds__(256) void lin_kernel(const float* __restrict__ x,
                                                  const float* __restrict__ W,
                                                  const float* __restrict__ b,
                                                  ushort* __restrict__ hc) {
  __shared__ float Ws[IND * H];  // 24 KB
  __shared__ float bs[H];
  int tid = threadIdx.x;
  for (int i = tid; i < IND * H; i += 256) Ws[i] = W[i];
  for (int i = tid; i < H; i += 256) bs[i] = b[i];
  __syncthreads();
  const int QPR = H / 4;  // 75 quads per row
  int total = NN * QPR;
  for (int idx = blockIdx.x * 256 + tid; idx < total; idx += gridDim.x * 256) {
    int n = idx / QPR;
    int f = (idx - n * QPR) * 4;
    float a0 = bs[f], a1 = bs[f + 1], a2 = bs[f + 2], a3 = bs[f + 3];
    const float* xr = x + n * IND;
#pragma unroll
    for (int k = 0; k < IND; ++k) {
      float xv = xr[k];
      const float* wk = &Ws[k * H + f];
      a0 = fmaf(xv, wk[0], a0);
      a1 = fmaf(xv, wk[1], a1);
      a2 = fmaf(xv, wk[2], a2);
      a3 = fmaf(xv, wk[3], a3);
    }
    uint2 o = make_uint2(packh(a0, a1), packh(a2, a3));
    *reinterpret_cast<uint2*>(hc + (long long)n * HCS + f) = o;
  }
}

// ---------------- aggregation: fp16 hc gather (8-deep), fp16 agg out ----------------

__global__ __launch_bounds__(192) void agg_kernel(const ushort* __restrict__ hc,
                                                  const int* __restrict__ offs,
                                                  const int* __restrict__ ssrc,
                                                  const float* __restrict__ sw,
                                                  ushort* __restrict__ agg) {
  int n = blockIdx.x;
  int t = threadIdx.x;
  if (t >= H / 2) return;
  int s = offs[n], e = offs[n + 1];
  float a0 = 0.f, a1 = 0.f;
  int i = s;
  for (; i + 7 < e; i += 8) {
    uint32_t u[8];
    float w[8];
#pragma unroll
    for (int j = 0; j < 8; ++j) {
      int sn = ssrc[i + j];
      w[j] = sw[i + j];
      u[j] = *reinterpret_cast<const uint32_t*>(hc + (long long)sn * HCS + 2 * t);
    }
#pragma unroll
    for (int j = 0; j < 8; ++j) {
      a0 = fmaf(w[j], h2f_lo(u[j]), a0);
      a1 = fmaf(w[j], h2f_hi(u[j]), a1);
    }
  }
  for (; i < e; ++i) {
    int sn = ssrc[i];
    float w = sw[i];
    uint32_t u = *reinterpret_cast<const uint32_t*>(hc + (long long)sn * HCS + 2 * t);
    a0 = fmaf(w, h2f_lo(u), a0);
    a1 = fmaf(w, h2f_hi(u), a1);
  }
  *reinterpret_cast<uint32_t*>(agg + (long long)n * KP1 + 2 * t) = packh(a0, a1);
}

// ---------------- fp16 MFMA GEMM, LDS-staged A, fused stats, XCD swizzle ----------------
// FUSE_BN: per-k relu(bns[k]*a + bnh[k]) on A fragments via packed v_pk_fma/v_pk_max.
// Both-sides swizzle => fragment a[i] holds k = kt*32 + lg*8 + j for all i.
// launch_bounds (256,4): NO spills (round-8 lesson: (256,6) -> VGPR=40 full spill, 5x).

template <bool FUSE_BN>
__global__ __launch_bounds__(256, 4) void gemm_mfma(
    const ushort* __restrict__ A, const ushort* __restrict__ Bp,
    const float* __restrict__ bias, ushort* __restrict__ C,
    float* __restrict__ sum, float* __restrict__ sq,
    int M, int Ntrue, int Ktiles, int KPAD, int Cstride, int ntiles,
    const ushort* __restrict__ bns, const ushort* __restrict__ bnh) {
  __shared__ ushort AL[2][128 * 32];
  int nwg = gridDim.x;
  int hw = blockIdx.x;
  int xcd = hw & 7, slot = hw >> 3;
  int q = nwg >> 3, r = nwg & 7;
  int logical = (xcd < r ? xcd * (q + 1) : r * (q + 1) + (xcd - r) * q) + slot;
  int mt = logical / ntiles;
  int nt = logical - mt * ntiles;

  int tid = threadIdx.x;
  int lane = tid & 63, wid = tid >> 6;
  int wm = wid >> 1, wn = wid & 1;
  int lm = lane & 15, lg = lane >> 4;
  long long bm = (long long)mt * 128;
  long long bn = (long long)nt * 128;

  int srow = lane >> 2;   // 0..15: row within the wave's 16-row staging segment
  int slotc = lane & 3;   // 16-byte chunk slot

  const ushort* Bb = Bp + (bn + wn * 64 + lm) * KPAD + lg * 8;

  f32x4 acc[4][4] = {};

  auto stageA = [&](int buf, int kt) {
    int k0 = kt * 32;
#pragma unroll
    for (int j = 0; j < 2; ++j) {
      int row = j * 64 + wid * 16 + srow;
      int cg = slotc ^ ((row >> 1) & 3);   // swizzled source chunk
      long long go = (bm + row) * KPAD + k0 + cg * 8;
      ushort* l = &AL[buf][(j * 64 + wid * 16) * 32];  // wave-uniform base
      __builtin_amdgcn_global_load_lds(
          (const __attribute__((address_space(1))) void*)(A + go),
          (__attribute__((address_space(3))) void*)l, 16, 0, 0);
    }
  };

  f16x8 bcur[4], bnxt[4];
  stageA(0, 0);
#pragma unroll
  for (int i = 0; i < 4; ++i)
    bcur[i] = *reinterpret_cast<const f16x8*>(Bb + (long long)i * 16 * KPAD);
  __syncthreads();

  for (int kt = 0; kt < Ktiles; ++kt) {
    int cur = kt & 1;
    int nk = kt + 1;
    if (nk < Ktiles) {
      stageA(nk & 1, nk);
#pragma unroll
      for (int i = 0; i < 4; ++i)
        bnxt[i] = *reinterpret_cast<const f16x8*>(Bb + (long long)i * 16 * KPAD + nk * 32);
    }
    f16x8 a[4];
#pragma unroll
    for (int i = 0; i < 4; ++i) {
      int row = wm * 64 + i * 16 + lm;
      int c = lg ^ ((row >> 1) & 3);
      a[i] = *reinterpret_cast<const f16x8*>(&AL[cur][row * 32 + c * 8]);
    }
    if constexpr (FUSE_BN) {
      int kbase = kt * 32 + lg * 8;
      f16x8 sv = *reinterpret_cast<const f16x8*>(bns + kbase);
      f16x8 hv = *reinterpret_cast<const f16x8*>(bnh + kbase);
#pragma unroll
      for (int i = 0; i < 4; ++i) a[i] = relu8(a[i] * sv + hv);
    }
#pragma unroll
    for (int mf = 0; mf < 4; ++mf)
#pragma unroll
      for (int nf = 0; nf < 4; ++nf)
        acc[mf][nf] = __builtin_amdgcn_mfma_f32_16x16x32_f16(a[mf], bcur[nf], acc[mf][nf], 0, 0, 0);
    __syncthreads();
#pragma unroll
    for (int i = 0; i < 4; ++i) bcur[i] = bnxt[i];
  }

  int colb = (int)bn + wn * 64 + lm;
#pragma unroll
  for (int nf = 0; nf < 4; ++nf) {
    int col = colb + nf * 16;
    bool cok = col < Ntrue;   // Ntrue even -> pair (col, col+1) valid together
    float bv = cok ? bias[col] : 0.f;
    float cs = 0.f, cq = 0.f;
#pragma unroll
    for (int mf = 0; mf < 4; ++mf) {
      int row0 = (int)bm + wm * 64 + mf * 16 + lg * 4;
      f32x4 v = acc[mf][nf];
#pragma unroll
      for (int e = 0; e < 4; ++e) {
        float w = v[e] + bv;
        bool ok = cok && (row0 + e < M);
        if (ok) {
          cs += w;
          cq = fmaf(w, w, cq);
        }
        float wp = __shfl_xor(w, 1);  // partner column's value, same row
        if (ok && ((lm & 1) == 0)) {
          *reinterpret_cast<uint32_t*>(&C[(long long)(row0 + e) * Cstride + col]) = packh(w, wp);
        }
      }
    }
    cs += __shfl_xor(cs, 16);
    cq += __shfl_xor(cq, 16);
    cs += __shfl_xor(cs, 32);
    cq += __shfl_xor(cq, 32);
    if (lg == 0 && cok) {
      atomicAdd(&sum[col], cs);
      atomicAdd(&sq[col], cq);
    }
  }
}

// ---------------- BN finalize ----------------
// Writes f32 scale/shift (and optionally packed fp16 copies for the fused gemm2 path).
// Zero-fills [C, Calloc) so padded-K fragments come out exactly 0 after fused BN.

__global__ void finalize_kernel(const float* __restrict__ sum, const float* __restrict__ sq,
                                const float* __restrict__ g, const float* __restrict__ be,
                                int C, int Calloc, float invM, float* __restrict__ scale,
                                float* __restrict__ shift, ushort* __restrict__ scaleh,
                                ushort* __restrict__ shifth) {
  int c = blockIdx.x * blockDim.x + threadIdx.x;
  if (c >= Calloc) return;
  float sc = 0.f, sh = 0.f;
  if (c < C) {
    float m = sum[c] * invM;
    float v = sq[c] * invM - m * m;
    sc = g[c] * rsqrtf(v + 1e-5f);
    sh = be[c] - m * sc;
  }
  scale[c] = sc;
  shift[c] = sh;
  if (scaleh) {
    scaleh[c] = f2h(sc);
    shifth[c] = f2h(sh);
  }
}

// bn2: fp16 u (stride KP1) -> fp16 hc (intermediate) or f32 hout (last)
template <bool LAST>
__global__ void bn2_kernel(const ushort* __restrict__ u_, const float* __restrict__ scale,
                           const float* __restrict__ shift, ushort* __restrict__ hc,
                           float* __restrict__ out) {
  const int QPR = H / 4;  // 75
  int total = NN * QPR;
  for (int idx = blockIdx.x * blockDim.x + threadIdx.x; idx < total;
       idx += gridDim.x * blockDim.x) {
    int r = idx / QPR;
    int c = (idx - r * QPR) * 4;
    uint2 u = *reinterpret_cast<const uint2*>(u_ + (long long)r * KP1 + c);
    float4 sc = *reinterpret_cast<const float4*>(scale + c);
    float4 sh = *reinterpret_cast<const float4*>(shift + c);
    float w0 = fmaf(h2f_lo(u.x), sc.x, sh.x);
    float w1 = fmaf(h2f_hi(u.x), sc.y, sh.y);
    float w2 = fmaf(h2f_lo(u.y), sc.z, sh.z);
    float w3 = fmaf(h2f_hi(u.y), sc.w, sh.w);
    if (LAST) {
      *reinterpret_cast<float4*>(out + (long long)r * H + c) = make_float4(w0, w1, w2, w3);
    } else {
      w0 = fmaxf(w0, 0.f);
      w1 = fmaxf(w1, 0.f);
      w2 = fmaxf(w2, 0.f);
      w3 = fmaxf(w3, 0.f);
      *reinterpret_cast<uint2*>(hc + (long long)r * HCS + c) =
          make_uint2(packh(w0, w1), packh(w2, w3));
    }
  }
}

// ---------------- graph pooling ----------------

__global__ void bounds_kernel(const int* __restrict__ batch, int* __restrict__ gstart) {
  int g = threadIdx.x;
  if (g > NG) return;
  if (g == NG) { gstart[NG] = NN; return; }
  int lo = 0, hi = NN;
  while (lo < hi) {
    int mid = (lo + hi) >> 1;
    if (batch[mid] < g) lo = mid + 1; else hi = mid;
  }
  gstart[g] = lo;
}

__global__ __launch_bounds__(320) void pool_kernel(const float* __restrict__ h,
                                                   const int* __restrict__ gstart,
                                                   float* __restrict__ xpool) {
  int g = blockIdx.x;
  int f = threadIdx.x;
  if (f >= H) return;
  int s = gstart[g], e = gstart[g + 1];
  float acc = 0.f;
  for (int r = s + blockIdx.y; r < e; r += gridDim.y) acc += h[(long long)r * H + f];
  atomicAdd(&xpool[g * H + f], acc);
}

// ---------------- driver ----------------

extern "C" void kernel_launch(void* const* d_in, const int* in_sizes, int n_in,
                              void* d_out, int out_size, void* d_ws, size_t ws_size,
                              hipStream_t stream) {
  const int*   batch = (const int*)d_in[0];
  const float* x     = (const float*)d_in[1];
  const int*   eidx  = (const int*)d_in[2];
  const float* eattr = (const float*)d_in[3];
  const float* linW  = (const float*)d_in[4];
  const float* linb  = (const float*)d_in[5];
  const float* W1s   = (const float*)d_in[6];
  const float* b1s   = (const float*)d_in[7];
  const float* g1s   = (const float*)d_in[8];
  const float* be1s  = (const float*)d_in[9];
  const float* W2s   = (const float*)d_in[10];
  const float* b2s   = (const float*)d_in[11];
  const float* gos   = (const float*)d_in[12];
  const float* bos   = (const float*)d_in[13];

  const int* esrc = eidx;
  const int* edst = eidx + NE;

  char* p = (char*)d_ws;
  auto alloc = [&](size_t bytes) {
    char* r = p;
    p += (bytes + 255) & ~(size_t)255;
    return r;
  };
  ushort* tb   = (ushort*)alloc((size_t)MP * KP2 * 2);   // t (fp16)
  ushort* ub   = (ushort*)alloc((size_t)MP * KP1 * 2);   // agg, reused as u (fp16)
  ushort* hc   = (ushort*)alloc((size_t)NN * HCS * 2);   // fp16 h copy
  ushort* W1p  = (ushort*)alloc((size_t)NL * NP1 * KP1 * 2);
  ushort* W2p  = (ushort*)alloc((size_t)NL * NP2 * KP2 * 2);
  int*    hist   = (int*)alloc((size_t)NN * 4);
  int*    offs   = (int*)alloc((size_t)(NN + 64) * 4);
  int*    cursor = (int*)alloc((size_t)NN * 4);
  int*    ssrc   = (int*)alloc((size_t)NE * 4);
  float*  sw     = (float*)alloc((size_t)NE * 4);
  int*    bsum   = (int*)alloc((size_t)(SCAN_B + 1) * 4);
  int*    bpre   = (int*)alloc((size_t)(SCAN_B + 1) * 4);
  float*  sum1   = (float*)alloc((size_t)(H2 * 2 + H * 2) * 4);
  float*  sq1    = sum1 + H2;
  float*  sum2   = sq1 + H2;
  float*  sq2    = sum2 + H;
  float*  scale1 = (float*)alloc((size_t)(KP2 * 2 + H * 2) * 4);
  float*  shift1 = scale1 + KP2;
  float*  scale2 = shift1 + KP2;
  float*  shift2 = scale2 + H;
  ushort* scaleh = (ushort*)alloc((size_t)KP2 * 2 * 2);  // packed fp16 scale/shift
  ushort* shifth = scaleh + KP2;
  int*    gstart = (int*)alloc((size_t)(NG + 1) * 4);
  size_t needed = (size_t)(p - (char*)d_ws);
  if (ws_size < needed) return;

  float* hout  = (float*)d_out;
  float* xpool = hout + (long long)NN * H;

  padzero_kernel<<<1024, 256, 0, stream>>>(tb, KP2, H2);
  padzero_kernel<<<1024, 256, 0, stream>>>(ub, KP1, H);

  packW1_kernel<<<(NL * NP1 * KP1 + 255) / 256, 256, 0, stream>>>(W1s, W1p);
  packW2_kernel<<<(NL * NP2 * KP2 + 255) / 256, 256, 0, stream>>>(W2s, W2p);

  hipMemsetAsync(hist, 0, (size_t)NN * 4, stream);
  hist_kernel<<<(NE + 255) / 256, 256, 0, stream>>>(edst, hist);
  scan1_kernel<<<SCAN_B, 1024, 0, stream>>>(hist, offs, bsum);
  scan2_kernel<<<1, 64, 0, stream>>>(bsum, bpre);
  scan3_kernel<<<SCAN_B, 1024, 0, stream>>>(bpre, offs, cursor);
  scatter_kernel<<<(NE + 255) / 256, 256, 0, stream>>>(esrc, edst, eattr, cursor, ssrc, sw);

  lin_kernel<<<4096, 256, 0, stream>>>(x, linW, linb, hc);

  const int MT = MP / 128;  // 391
  for (int i = 0; i < NL; ++i) {
    agg_kernel<<<NN, 192, 0, stream>>>(hc, offs, ssrc, sw, ub);
    hipMemsetAsync(sum1, 0, (size_t)(H2 * 2 + H * 2) * 4, stream);

    // t = agg @ W1 + b1  (fp16 out, stats fused)
    gemm_mfma<false><<<MT * (NP1 / 128), 256, 0, stream>>>(
        ub, W1p + (size_t)i * NP1 * KP1, b1s + (size_t)i * H2, tb,
        sum1, sq1, NN, H2, KP1 / 32, KP1, KP2, NP1 / 128, nullptr, nullptr);
    // BN1 scale/shift, incl. packed fp16 + zeroed K-pad for the fused gemm2 path
    finalize_kernel<<<(KP2 + 255) / 256, 256, 0, stream>>>(
        sum1, sq1, g1s + (size_t)i * H2, be1s + (size_t)i * H2, H2, KP2, 1.f / NN,
        scale1, shift1, scaleh, shifth);

    // u = relu(bn1(t)) @ W2 + b2 — BN1 fused into A-fragment path (no bn1 pass)
    gemm_mfma<true><<<MT * (NP2 / 128), 256, 0, stream>>>(
        tb, W2p + (size_t)i * NP2 * KP2, b2s + (size_t)i * H, ub,
        sum2, sq2, NN, H, KP2 / 32, KP2, KP1, NP2 / 128, scaleh, shifth);
    finalize_kernel<<<(H + 255) / 256, 256, 0, stream>>>(
        sum2, sq2, gos + (size_t)i * H, bos + (size_t)i * H, H, H, 1.f / NN,
        scale2, shift2, nullptr, nullptr);
    if (i < NL - 1) {
      bn2_kernel<false><<<4096, 256, 0, stream>>>(ub, scale2, shift2, hc, hout);
    } else {
      bn2_kernel<true><<<4096, 256, 0, stream>>>(ub, scale2, shift2, hc, hout);
    }
  }

  hipMemsetAsync(xpool, 0, (size_t)NG * H * 4, stream);
  bounds_kernel<<<1, 128, 0, stream>>>(batch, gstart);
  pool_kernel<<<dim3(NG, 8), 320, 0, stream>>>(hout, gstart, xpool);
}